// Round 3
// baseline (453.520 us; speedup 1.0000x reference)
//
#include <hip/hip_runtime.h>

// Problem constants (from reference): B=8192, K=512, C=16
#define B_SZ 8192
#define K_SZ 512
#define C_SZ 16

// R5 = R4 with the compile fix: __builtin_nontemporal_load rejects HIP's
// class-type int4; use a clang ext_vector_type(4) int instead (lowers to
// global_load_dwordx4 with nt policy).
//
// Full-stream row-sum. Post-mortem of R2/R3: both sparse-search variants
// live in the random-64B-fetch regime (~0.8-1.6M scattered line fetches at
// ~1.5-2 TB/s effective), costing ~96-113 us. But the mask rows are
// guaranteed contiguous leading-ones runs, so run_length == sum(row): no
// search is needed. Streaming the ENTIRE 256 MB mask with perfect
// line-granularity coalescing at ~6.3 TB/s costs ~41 us -- under the latency
// floor of any sparse probe scheme on this hardware.
//
// Layout: one 64-lane wave per example b. Lane (c = lane>>2, j = lane&3)
// sums row c reading int4s at row4[j + 4*i], i = 0..31: each instruction's
// 4-lane group covers one contiguous 64B line (16 lines = 1 KB per wave per
// instruction, zero overfetch). All 32 loads are independent -- no dependent
// miss chain. Lines are touched exactly once -> nontemporal loads.
// t = sum - 1; then gather logits[b][t][c], 16-wide shuffle log-softmax,
// one atomic per block.

typedef int iv4 __attribute__((ext_vector_type(4)));

__global__ __launch_bounds__(256) void rocloss_kernel(
    const float* __restrict__ logits,   // [B, K, C] f32
    const int*   __restrict__ target,   // [B] i32
    const int*   __restrict__ mask,     // [B, C, K] i32 (leading-ones rows)
    float*       __restrict__ out)      // [1] f32 (pre-zeroed)
{
    const int tid  = threadIdx.x;
    const int lane = tid & 63;
    const int wv   = tid >> 6;                 // wave within block, 0..3
    const int b    = blockIdx.x * 4 + wv;      // one wave per example
    const int c    = lane >> 2;                // candidate ending, 0..15
    const int j    = lane & 3;                 // sub-lane within 4-lane group

    const iv4* __restrict__ row4 =
        (const iv4*)(mask + (size_t)(b * C_SZ + c) * K_SZ);  // 128 iv4/row

    // ---- Stream the whole row, summing. 32 independent 16B loads/lane. ----
    int s0 = 0, s1 = 0, s2i = 0, s3 = 0;
    #pragma unroll 4
    for (int i = 0; i < 32; i += 4) {
        const iv4 q0 = __builtin_nontemporal_load(&row4[j + ((i + 0) << 2)]);
        const iv4 q1 = __builtin_nontemporal_load(&row4[j + ((i + 1) << 2)]);
        const iv4 q2 = __builtin_nontemporal_load(&row4[j + ((i + 2) << 2)]);
        const iv4 q3 = __builtin_nontemporal_load(&row4[j + ((i + 3) << 2)]);
        s0  += q0.x + q0.y + q0.z + q0.w;
        s1  += q1.x + q1.y + q1.z + q1.w;
        s2i += q2.x + q2.y + q2.z + q2.w;
        s3  += q3.x + q3.y + q3.z + q3.w;
    }
    int s = (s0 + s1) + (s2i + s3);
    s += __shfl_xor(s, 1);
    s += __shfl_xor(s, 2);                     // run length, replicated in group
    const int t = s - 1;                       // counter = run_length - 1

    // ---- Gather the logit at the last valid timestep: logits[b][t][c] ----
    // (4 lanes of a group hit the same address -> single request, broadcast)
    const float a = logits[((size_t)b * K_SZ + (size_t)t) * C_SZ + c];

    // ---- log-softmax across the 16 candidate groups (offsets 4..32) ----
    float m = a;
    #pragma unroll
    for (int off = 32; off >= 4; off >>= 1)
        m = fmaxf(m, __shfl_xor(m, off));
    const float e = __expf(a - m);
    float s2 = e;
    #pragma unroll
    for (int off = 32; off >= 4; off >>= 1)
        s2 += __shfl_xor(s2, off);
    const float lse = m + __logf(s2);          // logsumexp over 16 candidates

    // ---- loss_b = lse - a[target[b]]; mean over B; one atomic per block ----
    __shared__ float acc;
    if (tid == 0) acc = 0.0f;
    __syncthreads();
    if (c == target[b] && j == 0)
        atomicAdd(&acc, lse - a);              // 4 LDS atomics per block
    __syncthreads();
    if (tid == 0)
        atomicAdd(out, acc * (1.0f / (float)B_SZ));
}

extern "C" void kernel_launch(void* const* d_in, const int* in_sizes, int n_in,
                              void* d_out, int out_size, void* d_ws, size_t ws_size,
                              hipStream_t stream) {
    const float* logits = (const float*)d_in[0];   // [B,K,C] f32
    const int*   target = (const int*)d_in[1];     // [B] i32
    const int*   mask   = (const int*)d_in[2];     // [B,C,K] i32
    float* out = (float*)d_out;

    // d_out is poisoned with 0xAA before every launch; zero it for the atomics.
    (void)hipMemsetAsync(out, 0, sizeof(float), stream);

    // One wave per example: B/4 blocks of 256 threads = 8192 waves.
    rocloss_kernel<<<B_SZ / 4, 256, 0, stream>>>(logits, target, mask, out);
}